// Round 5
// baseline (704.027 us; speedup 1.0000x reference)
//
#include <hip/hip_runtime.h>
#include <cstdint>

// SparseMoE on MI355X (gfx950). fp32 inputs. B=2,S=2048 -> NTOK=4096 tokens,
// D=1024, E=8, H=4096, top_k=2.
// R5: 4 contexts/CU for both GEMMs. Evidence chain: R2 (2 blocks/CU) beat
// R3/R4 (1 block/CU) regardless of tile size / pipeline depth -> fill rate
// scales with independent co-resident blocks. m97 reference: same 2-barrier
// structure at ~3 blocks/CU sustains 13.3 TB/s LDS-fill vs our 7.2 at 2.
// Changes: BK=32 (dbuf LDS 32 KiB -> LDS cap 5/CU, VGPR cap 4/CU) with
// re-derived XOR swizzle; proj split-K=2 (active blocks 512->1024) with fp32
// atomicAdd partials into the freed xg+ybuf regions. Tile stays 128x128
// (intensity 65.5 flops/B unchanged), loop stays the proven 2-phase dbuf.

#define DEV __device__ __forceinline__

typedef __attribute__((ext_vector_type(8))) short short8;   // 8 x bf16
typedef __attribute__((ext_vector_type(4))) float floatx4;  // MFMA accumulator

constexpr int D_ = 1024, E_ = 8, H_ = 4096;
constexpr int NTOK = 4096;
constexpr int CAP  = 4096;
constexpr int TOTSLOT = NTOK * 2;

// ---- workspace layout (bytes); ~160.3 MB, proven available ----
constexpr size_t O_COUNT = 0;
constexpr size_t O_OFFS  = 64;
constexpr size_t O_BTOK  = 128;
constexpr size_t O_BGATE = O_BTOK  + (size_t)E_ * CAP * 4;
constexpr size_t O_PAIR  = O_BGATE + (size_t)E_ * CAP * 4;
constexpr size_t O_XG    = (O_PAIR + (size_t)NTOK * 2 * 4 + 255) & ~(size_t)255;
constexpr size_t O_HBUF  = O_XG   + (size_t)TOTSLOT * D_ * 2;  // 16 MB
constexpr size_t O_YBUF  = O_HBUF + (size_t)TOTSLOT * H_ * 2;  // 64 MB
constexpr size_t O_WT    = O_YBUF + (size_t)TOTSLOT * D_ * 2;  // 16 MB
constexpr size_t WS_NEED = O_WT   + (size_t)E_ * D_ * H_ * 2;  // + 64 MB
// During proj, xg (16 MB) and ybuf (16 MB) are free: they hold the two
// halves of the fp32 partial-sum buffer pb0/pb1 (4096 slots x 1024 each).

DEV float b2f(unsigned short u) {
    union { unsigned int i; float f; } v; v.i = ((unsigned int)u) << 16; return v.f;
}
DEV unsigned int f2b(float f) {  // round-to-nearest-even, low 16 bits
    union { float f; unsigned int i; } v; v.f = f;
    unsigned int r = v.i + 0x7fffu + ((v.i >> 16) & 1u);
    return (r >> 16) & 0xffffu;
}
DEV float gelu_tanh(float x) {
    float u = 0.7978845608028654f * (x + 0.044715f * x * x * x);
    u = fminf(fmaxf(u, -20.f), 20.f);
    float e = __expf(2.f * u);
    float t = (e - 1.f) / (e + 1.f);
    return 0.5f * x * (1.f + t);
}

// async global->LDS, 16 B per lane (dest = wave-uniform base + lane*16)
typedef __attribute__((address_space(3))) unsigned int lds_u32_t;
typedef const __attribute__((address_space(1))) unsigned int g_u32_t;
DEV void gload16(const unsigned short* g, const unsigned short* l) {
    __builtin_amdgcn_global_load_lds((g_u32_t*)(size_t)g,
                                     (lds_u32_t*)(unsigned int)(size_t)l, 16, 0, 0);
}

// ---------------------------------------------------------------------------
__global__ __launch_bounds__(64) void zero_counts(int* counts) {
    if (threadIdx.x < E_) counts[threadIdx.x] = 0;
}

// Router: one wave per token, fp64 accumulation (minimizes top-k flips vs the
// np fp32 reference — the dominant correctness risk; proven).
__global__ __launch_bounds__(256) void router_kernel(
    const float* __restrict__ x, const float* __restrict__ noise,
    const float* __restrict__ w_route, const float* __restrict__ b_route,
    const float* __restrict__ w_noise, const float* __restrict__ b_noise,
    float* __restrict__ out,  // gate1 at element offset NTOK*D_
    int* counts, int* btok, float* bgate, int* pairs)
{
    int wave = threadIdx.x >> 6, lane = threadIdx.x & 63;
    int t = blockIdx.x * 4 + wave;

    double racc[E_], nacc[E_];
#pragma unroll
    for (int e = 0; e < E_; e++) { racc[e] = 0.0; nacc[e] = 0.0; }

#pragma unroll 4
    for (int i = 0; i < D_ / 64; i++) {
        int j = i * 64 + lane;
        float xv = x[(size_t)t * D_ + j];
        const float* wr = w_route + (size_t)j * E_;
        const float* wn = w_noise + (size_t)j * E_;
        float4 a0 = ((const float4*)wr)[0], a1 = ((const float4*)wr)[1];
        float4 c0 = ((const float4*)wn)[0], c1 = ((const float4*)wn)[1];
        const float rv[8] = {a0.x,a0.y,a0.z,a0.w,a1.x,a1.y,a1.z,a1.w};
        const float nv[8] = {c0.x,c0.y,c0.z,c0.w,c1.x,c1.y,c1.z,c1.w};
#pragma unroll
        for (int e = 0; e < E_; e++) {
            racc[e] += (double)(xv * rv[e]);
            nacc[e] += (double)(xv * nv[e]);
        }
    }
#pragma unroll
    for (int off = 32; off > 0; off >>= 1)
#pragma unroll
        for (int e = 0; e < E_; e++) {
            racc[e] += __shfl_down(racc[e], off);
            nacc[e] += __shfl_down(nacc[e], off);
        }

    if (lane == 0) {
        double nz[E_];
#pragma unroll
        for (int e = 0; e < E_; e++) {
            double lg = racc[e] + (double)b_route[e];
            double nl = nacc[e] + (double)b_noise[e];
            double sp = (nl > 0.0) ? nl + log1p(exp(-nl)) : log1p(exp(nl));
            nz[e] = lg + (double)noise[(size_t)t * E_ + e] * sp;
        }
        double mx = nz[0];
#pragma unroll
        for (int e = 1; e < E_; e++) mx = fmax(mx, nz[e]);
        double se = 0.0, ex[E_];
#pragma unroll
        for (int e = 0; e < E_; e++) { ex[e] = exp(nz[e] - mx); se += ex[e]; }
#pragma unroll
        for (int e = 0; e < E_; e++)
            out[(size_t)NTOK * D_ + (size_t)t * E_ + e] = (float)(ex[e] / se);
        // top-2 (strict > keeps lower index on ties, matching lax.top_k)
        double v0 = -1e300, v1 = -1e300; int i0 = 0, i1 = 0;
#pragma unroll
        for (int e = 0; e < E_; e++) {
            double v = nz[e];
            if (v > v0) { v1 = v0; i1 = i0; v0 = v; i0 = e; }
            else if (v > v1) { v1 = v; i1 = e; }
        }
        double g0 = 1.0 / (1.0 + exp(v1 - v0));
        float  g1 = (float)(1.0 - g0);
        int l0 = atomicAdd(&counts[i0], 1);
        int l1 = atomicAdd(&counts[i1], 1);
        btok[i0 * CAP + l0] = t;  bgate[i0 * CAP + l0] = (float)g0;
        btok[i1 * CAP + l1] = t;  bgate[i1 * CAP + l1] = g1;
        pairs[2 * t]     = (i0 << 16) | l0;
        pairs[2 * t + 1] = (i1 << 16) | l1;
    }
}

__global__ __launch_bounds__(64) void offsets_kernel(const int* counts, int* offs) {
    if (threadIdx.x == 0) {
        int a = 0;
        for (int e = 0; e < E_; e++) { offs[e] = a; a += counts[e]; }
        offs[E_] = a;
    }
}

// Scatter x rows (fp32 -> bf16) to both selected slots. One block per token:
// x read exactly once, coalesced; no dead blocks.
__global__ __launch_bounds__(256) void gather_x(
    const float* __restrict__ x, const int* __restrict__ pairs,
    const int* __restrict__ offs, unsigned short* __restrict__ xg)
{
    int t = blockIdx.x;
    int c = threadIdx.x * 4;
    float4 v = *(const float4*)(x + (size_t)t * D_ + c);
    uint2 o;
    o.x = f2b(v.x) | (f2b(v.y) << 16);
    o.y = f2b(v.z) | (f2b(v.w) << 16);
    int p0 = pairs[2 * t], p1 = pairs[2 * t + 1];
    size_t r0 = (size_t)(offs[p0 >> 16] + (p0 & 0xffff)) * D_;
    size_t r1 = (size_t)(offs[p1 >> 16] + (p1 & 0xffff)) * D_;
    *(uint2*)(xg + r0 + c) = o;
    *(uint2*)(xg + r1 + c) = o;
}

// transpose+convert: w [E][K][N] fp32 -> wT [E][N][K] bf16. 64x64 LDS tiles.
__global__ __launch_bounds__(256) void transpose_w(
    const float* __restrict__ w, unsigned short* __restrict__ wT, int K, int N)
{
    __shared__ unsigned short t[64][65];
    const int e  = blockIdx.z;
    const int k0 = blockIdx.y * 64;
    const int n0 = blockIdx.x * 64;
    const int r  = threadIdx.x >> 2;          // 0..63
    const int c4 = (threadIdx.x & 3) * 16;    // 0,16,32,48
    const float* src = w + ((size_t)e * K + k0 + r) * N + n0 + c4;
#pragma unroll
    for (int i = 0; i < 4; i++) {
        float4 v = ((const float4*)src)[i];
        t[r][c4 + 4*i + 0] = (unsigned short)f2b(v.x);
        t[r][c4 + 4*i + 1] = (unsigned short)f2b(v.y);
        t[r][c4 + 4*i + 2] = (unsigned short)f2b(v.z);
        t[r][c4 + 4*i + 3] = (unsigned short)f2b(v.w);
    }
    __syncthreads();
    unsigned short* dstp = wT + ((size_t)e * N + n0 + r) * K + k0 + c4;
    unsigned short tmp[16];
#pragma unroll
    for (int i = 0; i < 16; i++) tmp[i] = t[c4 + i][r];
#pragma unroll
    for (int h = 0; h < 2; h++) {
        uint4 pk;
        pk.x = (unsigned int)tmp[8*h+0] | ((unsigned int)tmp[8*h+1] << 16);
        pk.y = (unsigned int)tmp[8*h+2] | ((unsigned int)tmp[8*h+3] << 16);
        pk.z = (unsigned int)tmp[8*h+4] | ((unsigned int)tmp[8*h+5] << 16);
        pk.w = (unsigned int)tmp[8*h+6] | ((unsigned int)tmp[8*h+7] << 16);
        ((uint4*)dstp)[h] = pk;
    }
}

// zero the fp32 partial buffer (both 16 MB halves); runs after FC frees xg.
__global__ __launch_bounds__(256) void zero_pbuf(float* pb0, float* pb1) {
    size_t i = ((size_t)blockIdx.x * 256 + threadIdx.x) * 4;
    float4 z = {0.f, 0.f, 0.f, 0.f};
    *(float4*)(pb0 + i) = z;
    *(float4*)(pb1 + i) = z;
}

// ---- grouped GEMM, 128x128 tile, BK=32, 2-phase dbuf, 32 KiB LDS -----------
// 4 waves (2x2 of 64x64), 16x16x32 bf16 MFMA. Per K-step: stage next 32-k
// tile into buf^1 (4 gload16/wave), 16 MFMA on buf, one __syncthreads.
// 32 KiB LDS + ~108 VGPR -> 4 co-resident blocks/CU (the R2->R4 lever).
// Swizzle (BK=32, 4 k-slots of 8): LDS slot s of row r holds global k-chunk
// s ^ ((r>>1)&3); compute reads &As[Ra*32 + ((quad ^ ((Ra>>1)&3))*8)].
// Per 16-lane wave quarter: 8 distinct 4-bank slots x 2 lanes = conflict-free.
// proj (FC=false): split-K=KHALVES=2, halves atomicAdd fp32 partials into
// pb0/pb1 (bias added by kh==0 half only; gate applied per half).
template <int KD, int ND, bool FC, int KHALVES>
__global__ __launch_bounds__(256) void moe_gemm32(
    const unsigned short* __restrict__ A,    // [TOTSLOT][KD] bf16 (xg or hbuf)
    const unsigned short* __restrict__ wT,   // [E][ND][KD] bf16
    const float* __restrict__ bias32,        // [E][ND] fp32 (direct input)
    unsigned short* __restrict__ dstBf,      // FC: [TOTSLOT][ND] bf16
    float* __restrict__ pb0, float* __restrict__ pb1,  // proj fp32 partials
    const int* __restrict__ counts, const int* __restrict__ offs,
    const float* __restrict__ bgate)
{
    const int lin = blockIdx.x;
    const int xcd = lin & 7, slot = lin >> 3;
    int e, mt, nt, kh;
    if (FC) {            // ND=4096: 32 n-tiles, 4 per XCD, nsub fastest
        nt = xcd * 4 + (slot & 3);
        mt = (slot >> 2) & 31;
        e  = slot >> 7;
        kh = 0;
    } else {             // ND=1024: 8 n-tiles, 1 per XCD; split-K halves
        nt = xcd;
        mt = slot & 31;
        kh = (slot >> 5) & 1;
        e  = slot >> 6;
    }
    const int cnt = counts[e];
    const int m0 = mt * 128;
    if (m0 >= cnt) return;
    const int n0 = nt * 128;
    const int off = offs[e];

    constexpr int KB = KD / KHALVES;     // k-range per block
    const int kbase = kh * KB;

    // [2 buffers][A 128x32 | B 128x32] = 32 KiB static LDS
    __shared__ unsigned short smem[2][2 * 128 * 32];
    constexpr int BOFF = 128 * 32;

    const int tid = threadIdx.x;
    const int waveid = tid >> 6, lane = tid & 63;
    // staging: per wave 2 A-chunks + 2 B-chunks; chunk = 16 rows x 32 shorts
    const int srow16 = lane >> 2;        // row within 16-row chunk
    const int sslot  = lane & 3;         // k-slot (8 shorts = 16 B)

    const unsigned short* aAddr[2];
    const unsigned short* bAddr[2];
#pragma unroll
    for (int c = 0; c < 2; c++) {
        const int rl = (waveid * 2 + c) * 16 + srow16;   // tile-local row
        const int g  = sslot ^ ((rl >> 1) & 3);          // pre-swizzled chunk
        int ar = m0 + rl;
        if (ar > cnt - 1) ar = cnt - 1;
        aAddr[c] = A + (size_t)(off + ar) * KD + kbase + g * 8;
        const int br = n0 + rl;
        bAddr[c] = wT + ((size_t)e * ND + br) * KD + kbase + g * 8;
    }

    const int wm = (waveid & 1) * 64, wn = (waveid >> 1) * 64;
    const int lrow = lane & 15, quad = lane >> 4;

    floatx4 acc[4][4];
#pragma unroll
    for (int fm = 0; fm < 4; fm++)
#pragma unroll
        for (int fn = 0; fn < 4; fn++) acc[fm][fn] = (floatx4)0.f;

    const int nk = KB / 32;              // FC: 32, proj-half: 64

    // prologue: stage K-tile 0 into buffer 0
#pragma unroll
    for (int c = 0; c < 2; c++) {
        gload16(aAddr[c], &smem[0][(waveid * 2 + c) * 512]);
        gload16(bAddr[c], &smem[0][BOFF + (waveid * 2 + c) * 512]);
    }
    __syncthreads();

    for (int t = 0; t < nk; ++t) {
        const int cur = t & 1;
        // phase A: issue next K-tile's async loads into the other buffer
        if (t + 1 < nk) {
            const int k0 = (t + 1) * 32;
#pragma unroll
            for (int c = 0; c < 2; c++) {
                gload16(aAddr[c] + k0, &smem[cur ^ 1][(waveid * 2 + c) * 512]);
                gload16(bAddr[c] + k0, &smem[cur ^ 1][BOFF + (waveid * 2 + c) * 512]);
            }
        }
        // phase B: compute on current buffer (load latency hides under this
        // plus the other co-resident blocks' compute)
        const unsigned short* As = &smem[cur][0];
        const unsigned short* Bs = &smem[cur][BOFF];
        short8 af[4], bfr[4];
#pragma unroll
        for (int f = 0; f < 4; f++) {
            const int Ra = wm + f * 16 + lrow;
            const int Rb = wn + f * 16 + lrow;
            af[f]  = *(const short8*)&As[Ra * 32 + ((quad ^ ((Ra >> 1) & 3)) * 8)];
            bfr[f] = *(const short8*)&Bs[Rb * 32 + ((quad ^ ((Rb >> 1) & 3)) * 8)];
        }
#pragma unroll
        for (int fm = 0; fm < 4; fm++)
#pragma unroll
            for (int fn = 0; fn < 4; fn++)
                acc[fm][fn] = __builtin_amdgcn_mfma_f32_16x16x32_bf16(
                    af[fm], bfr[fn], acc[fm][fn], 0, 0, 0);
        // single drain per K-step: vmcnt(0)+lgkmcnt(0)+barrier, then flip
        __syncthreads();
    }

    // Epilogue. C/D layout: col = lane&15, row = quad*4 + reg.
    const int gc = n0 + wn + lrow;
    float bcol[4];
#pragma unroll
    for (int fn = 0; fn < 4; fn++) bcol[fn] = bias32[(size_t)e * ND + gc + fn * 16];

#pragma unroll
    for (int fm = 0; fm < 4; fm++) {
        int srow0 = m0 + wm + fm * 16 + quad * 4;
#pragma unroll
        for (int r = 0; r < 4; r++) {
            int srow = srow0 + r;
            if (srow < cnt) {
                const int oslot = off + srow;
                if (FC) {
                    size_t base = (size_t)oslot * ND;
#pragma unroll
                    for (int fn = 0; fn < 4; fn++) {
                        float v = acc[fm][fn][r] + bcol[fn];
                        dstBf[base + gc + fn * 16] = (unsigned short)f2b(gelu_tanh(v));
                    }
                } else {
                    float gt = bgate[e * CAP + srow];
                    float* pb = (oslot < NTOK)
                        ? pb0 + (size_t)oslot * ND
                        : pb1 + (size_t)(oslot - NTOK) * ND;
#pragma unroll
                    for (int fn = 0; fn < 4; fn++) {
                        float v = (acc[fm][fn][r] + (kh == 0 ? bcol[fn] : 0.f)) * gt;
                        atomicAdd(&pb[gc + fn * 16], v);
                    }
                }
            }
        }
    }
}

// out[t] = pbuf[slot0(t)] + pbuf[slot1(t)]  (gates+bias already applied)
__global__ __launch_bounds__(256) void combine_kernel(
    const float* __restrict__ pb0, const float* __restrict__ pb1,
    const int* __restrict__ pairs, const int* __restrict__ offs,
    float* __restrict__ out)
{
    int t = blockIdx.x;
    int p0 = pairs[2 * t], p1 = pairs[2 * t + 1];
    int s0 = offs[p0 >> 16] + (p0 & 0xffff);
    int s1 = offs[p1 >> 16] + (p1 & 0xffff);
    int c = threadIdx.x * 4;
    const float* a = (s0 < NTOK ? pb0 + (size_t)s0 * D_
                                : pb1 + (size_t)(s0 - NTOK) * D_) + c;
    const float* b = (s1 < NTOK ? pb0 + (size_t)s1 * D_
                                : pb1 + (size_t)(s1 - NTOK) * D_) + c;
    float4 va = *(const float4*)a;
    float4 vb = *(const float4*)b;
    float4 o;
    o.x = va.x + vb.x; o.y = va.y + vb.y; o.z = va.z + vb.z; o.w = va.w + vb.w;
    *(float4*)(out + (size_t)t * D_ + c) = o;
}

// ---------------------------------------------------------------------------
extern "C" void kernel_launch(void* const* d_in, const int* in_sizes, int n_in,
                              void* d_out, int out_size, void* d_ws, size_t ws_size,
                              hipStream_t stream) {
    if (ws_size < WS_NEED) return;  // diagnostic: output stays 0

    const float* x       = (const float*)d_in[0];
    const float* noise   = (const float*)d_in[1];
    const float* w_route = (const float*)d_in[2];
    const float* b_route = (const float*)d_in[3];
    const float* w_noise = (const float*)d_in[4];
    const float* b_noise = (const float*)d_in[5];
    const float* w_fc    = (const float*)d_in[6];
    const float* b_fc    = (const float*)d_in[7];
    const float* w_proj  = (const float*)d_in[8];
    const float* b_proj  = (const float*)d_in[9];

    char* ws = (char*)d_ws;
    int*   counts = (int*)(ws + O_COUNT);
    int*   offs   = (int*)(ws + O_OFFS);
    int*   btok   = (int*)(ws + O_BTOK);
    float* bgate  = (float*)(ws + O_BGATE);
    int*   pairs  = (int*)(ws + O_PAIR);
    unsigned short* xg   = (unsigned short*)(ws + O_XG);
    unsigned short* hbuf = (unsigned short*)(ws + O_HBUF);
    unsigned short* wT   = (unsigned short*)(ws + O_WT);
    // fp32 partial buffers for proj split-K (reuse xg + ybuf regions)
    float* pb0 = (float*)(ws + O_XG);    // slots 0..4095
    float* pb1 = (float*)(ws + O_YBUF);  // slots 4096..8191

    zero_counts<<<dim3(1), dim3(64), 0, stream>>>(counts);
    router_kernel<<<dim3(NTOK / 4), dim3(256), 0, stream>>>(
        x, noise, w_route, b_route, w_noise, b_noise, (float*)d_out,
        counts, btok, bgate, pairs);
    offsets_kernel<<<dim3(1), dim3(64), 0, stream>>>(counts, offs);
    gather_x<<<dim3(NTOK), dim3(256), 0, stream>>>(x, pairs, offs, xg);

    // FC: w_fc [E][D][H] -> wT [E][H][D]; GEMM 128x128, BK=32
    transpose_w<<<dim3(H_ / 64, D_ / 64, E_), dim3(256), 0, stream>>>(w_fc, wT, D_, H_);
    moe_gemm32<D_, H_, true, 1><<<dim3(8 * 32 * 32), dim3(256), 0, stream>>>(
        xg, wT, b_fc, hbuf, pb0, pb1, counts, offs, bgate);

    // zero fp32 partials (xg is free after FC consumed it)
    zero_pbuf<<<dim3(NTOK), dim3(256), 0, stream>>>(pb0, pb1);

    // proj: w_proj [E][H][D] -> wT [E][D][H]; GEMM 128x128, BK=32, split-K=2
    transpose_w<<<dim3(D_ / 64, H_ / 64, E_), dim3(256), 0, stream>>>(w_proj, wT, H_, D_);
    moe_gemm32<H_, D_, false, 2><<<dim3(8 * 32 * 2 * 8), dim3(256), 0, stream>>>(
        hbuf, wT, b_proj, nullptr, pb0, pb1, counts, offs, bgate);

    combine_kernel<<<dim3(NTOK), dim3(256), 0, stream>>>(pb0, pb1, pairs, offs, (float*)d_out);
}